// Round 3
// baseline (122.609 us; speedup 1.0000x reference)
//
#include <hip/hip_runtime.h>
#include <cstdint>
#include <cstddef>

#define BATCH   16384
#define NFEAT   2048
#define KD      1024     // num_used (= K of GEMM1, = rows of W)
#define NNODE   1024     // num_leaves / node columns
#define NCLS    100

typedef __attribute__((ext_vector_type(8))) __bf16 bf16x8;
typedef __attribute__((ext_vector_type(4))) float f32x4;
typedef __attribute__((ext_vector_type(4))) unsigned int u32x4;

__device__ __forceinline__ unsigned short f2bf(float f) {
  union { float f; unsigned int u; } v; v.f = f;
  unsigned int r = v.u + 0x7FFFu + ((v.u >> 16) & 1u);
  return (unsigned short)(r >> 16);
}
__device__ __forceinline__ float bf2f(unsigned short h) {
  union { unsigned int u; float f; } v; v.u = ((unsigned int)h) << 16;
  return v.f;
}

__device__ __forceinline__ void gload_lds16(const void* g, void* l) {
  __builtin_amdgcn_global_load_lds((__attribute__((address_space(1))) void*)g,
                                   (__attribute__((address_space(3))) void*)l,
                                   16, 0, 0);
}

__device__ __forceinline__ bf16x8 ld_frag(const unsigned short* p) {
  return __builtin_bit_cast(bf16x8, *(const u32x4*)p);
}

// ---- prep: extract idx[i] = argmax of one-hot mask row i ----
__global__ void k_idx(const float* __restrict__ mask, int* __restrict__ idx) {
  int r = blockIdx.x, t = threadIdx.x;
  for (int c = t; c < NFEAT; c += 256)
    if (mask[(size_t)r * NFEAT + c] > 0.5f) idx[r] = c;
}

// ---- prep: WT[n][k] = bf16(W[k][n]) ----
__global__ void k_wt(const float* __restrict__ W, unsigned short* __restrict__ WT) {
  __shared__ float tile[32][33];
  int n0 = blockIdx.x * 32, k0 = blockIdx.y * 32;
  int tx = threadIdx.x, ty = threadIdx.y; // (32, 8)
  for (int i = ty; i < 32; i += 8)
    tile[i][tx] = W[(size_t)(k0 + i) * NNODE + n0 + tx];
  __syncthreads();
  for (int i = ty; i < 32; i += 8)
    WT[(size_t)(n0 + i) * KD + k0 + tx] = f2bf(tile[tx][i]);
}

// ---- prep: PT[n][l] = bf16(softmax(pi[l,:])[n]), zero-padded to 128 rows ----
__global__ void k_probs(const float* __restrict__ pi, unsigned short* __restrict__ PT) {
  int l = blockIdx.x, t = threadIdx.x; // 64 threads
  float v0 = (t < NCLS) ? pi[(size_t)l * NCLS + t] : -1e30f;
  float v1 = (t + 64 < NCLS) ? pi[(size_t)l * NCLS + t + 64] : -1e30f;
  float m = fmaxf(v0, v1);
  for (int o = 32; o; o >>= 1) m = fmaxf(m, __shfl_xor(m, o));
  float e0 = (t < NCLS) ? __expf(v0 - m) : 0.f;
  float e1 = (t + 64 < NCLS) ? __expf(v1 - m) : 0.f;
  float s = e0 + e1;
  for (int o = 32; o; o >>= 1) s += __shfl_xor(s, o);
  float inv = 1.f / s;
  PT[(size_t)t * NNODE + l] = f2bf(e0 * inv);
  PT[(size_t)(t + 64) * NNODE + l] = f2bf(e1 * inv);
}

// ---- gather: X[b][i] = bf16(features[b][idx[i]]) ----
__global__ void k_gather(const float* __restrict__ F, const int* __restrict__ idx,
                         unsigned short* __restrict__ X) {
  __shared__ int idxs[KD];
  int b = blockIdx.x, t = threadIdx.x;
  for (int j = t; j < KD; j += 256) idxs[j] = idx[j];
  __syncthreads();
  const float* row = F + (size_t)b * NFEAT;
  int i0 = t * 4;
  ushort4 o;
  o.x = f2bf(row[idxs[i0 + 0]]);
  o.y = f2bf(row[idxs[i0 + 1]]);
  o.z = f2bf(row[idxs[i0 + 2]]);
  o.w = f2bf(row[idxs[i0 + 3]]);
  *(ushort4*)(X + (size_t)b * KD + i0) = o;
}

// ============ GEMM1: D = sigmoid(X @ WT^T + b) ============
// 256x256 tile, BK=64, 512 threads = 8 waves (2M x 4N), wave tile 128x64.
// 8-phase schedule (T3+T4): 2 K-tiles per 8 phases, counted vmcnt(4), raw
// s_barrier, XOR-swizzled LDS (T2 via pre-swizzled source), setprio (T5).
// LDS: [dbuf][half] 128x64 panels for A and B = 4*2*16KB = 128 KiB.
__global__ __launch_bounds__(512, 2)
void k_gemm1(const unsigned short* __restrict__ A, const unsigned short* __restrict__ Bt,
             const float* __restrict__ bias, unsigned short* __restrict__ D) {
  __shared__ __align__(16) unsigned short Al[2][2][128 * 64];
  __shared__ __align__(16) unsigned short Bl[2][2][128 * 64];
  const int t = threadIdx.x;
  const int lane = t & 63;
  const int wave = t >> 6;
  const int m0 = blockIdx.x * 256;
  const int n0 = blockIdx.y * 256;
  const int wm = (wave >> 2) * 128;   // 0 or 128 -> A half
  const int wn = (wave & 3) * 64;     // 0,64,128,192
  const int ah = wm >> 7;
  const int bhh = wn >> 7;            // B half
  const int bo = wn & 64;             // col offset within B half
  const int cl = lane & 15, klb = (lane >> 4) * 8, rsel = (lane & 7) * 8;

  // staging geometry: thread t covers rows sr, sr+64 of a 128-row half panel
  const int sr = t >> 3;
  const int sc = ((t & 7) ^ (sr & 7)) * 8;   // pre-swizzled source col (elems)
  const int sdst = (t & ~63) * 8;            // linear LDS dest (elems)

  const unsigned short* Abase = A + (size_t)(m0 + sr) * KD + sc;
  const unsigned short* Bbase = Bt + (size_t)(n0 + sr) * KD + sc;

  auto stA = [&](int kt, int half, int p) {
    const unsigned short* g = Abase + (size_t)half * 128 * KD + (size_t)(kt & 15) * 64;
    unsigned short* d = &Al[p][half][sdst];
    gload_lds16(g, d);
    gload_lds16(g + (size_t)64 * KD, d + 4096);
  };
  auto stB = [&](int kt, int half, int p) {
    const unsigned short* g = Bbase + (size_t)half * 128 * KD + (size_t)(kt & 15) * 64;
    unsigned short* d = &Bl[p][half][sdst];
    gload_lds16(g, d);
    gload_lds16(g + (size_t)64 * KD, d + 4096);
  };

  f32x4 acc[8][4];
#pragma unroll
  for (int i = 0; i < 8; ++i)
#pragma unroll
    for (int j = 0; j < 4; ++j) acc[i][j] = (f32x4)0.f;

  // prologue: buf0 full (4 units) + buf1 A-halves (2 units); force buf0 landed
  stA(0, 0, 0); stA(0, 1, 0); stB(0, 0, 0); stB(0, 1, 0);
  stA(1, 0, 1); stA(1, 1, 1);
  asm volatile("s_waitcnt vmcnt(4)" ::: "memory");
  __builtin_amdgcn_sched_barrier(0);
  __builtin_amdgcn_s_barrier();

  auto ktile = [&](int p, int kt) {
    const unsigned short* Ab = &Al[p][ah][0];
    const unsigned short* Bb = &Bl[p][bhh][0];
    const int q = p ^ 1;
    bf16x8 a0[8], a1[8], b0[4], b1[4];
    // ---------- phase 1: read kk0 frags | stage B0(kt+1)->q | MFMA m0-3 kk0
#pragma unroll
    for (int m = 0; m < 8; ++m) a0[m] = ld_frag(Ab + (m * 16 + cl) * 64 + (klb ^ rsel));
#pragma unroll
    for (int n = 0; n < 4; ++n) b0[n] = ld_frag(Bb + (bo + n * 16 + cl) * 64 + (klb ^ rsel));
    stB(kt + 1, 0, q);
    __builtin_amdgcn_s_barrier();
    asm volatile("s_waitcnt lgkmcnt(0)" ::: "memory");
    __builtin_amdgcn_sched_barrier(0);
    __builtin_amdgcn_s_setprio(1);
#pragma unroll
    for (int m = 0; m < 4; ++m)
#pragma unroll
      for (int n = 0; n < 4; ++n)
        acc[m][n] = __builtin_amdgcn_mfma_f32_16x16x32_bf16(a0[m], b0[n], acc[m][n], 0, 0, 0);
    __builtin_amdgcn_s_setprio(0);
    __builtin_amdgcn_sched_barrier(0);
    __builtin_amdgcn_s_barrier();
    // ---------- phase 2: read kk1 frags | stage B1(kt+1)->q | MFMA m4-7 kk0
#pragma unroll
    for (int m = 0; m < 8; ++m) a1[m] = ld_frag(Ab + (m * 16 + cl) * 64 + ((32 + klb) ^ rsel));
#pragma unroll
    for (int n = 0; n < 4; ++n) b1[n] = ld_frag(Bb + (bo + n * 16 + cl) * 64 + ((32 + klb) ^ rsel));
    stB(kt + 1, 1, q);
    __builtin_amdgcn_s_barrier();
    asm volatile("s_waitcnt lgkmcnt(0)" ::: "memory");
    __builtin_amdgcn_sched_barrier(0);
    __builtin_amdgcn_s_setprio(1);
#pragma unroll
    for (int m = 4; m < 8; ++m)
#pragma unroll
      for (int n = 0; n < 4; ++n)
        acc[m][n] = __builtin_amdgcn_mfma_f32_16x16x32_bf16(a0[m], b0[n], acc[m][n], 0, 0, 0);
    __builtin_amdgcn_s_setprio(0);
    __builtin_amdgcn_sched_barrier(0);
    __builtin_amdgcn_s_barrier();
    // ---------- phase 3: stage A0(kt+2)->p (A-half0 of p read-free since ph2) | MFMA m0-3 kk1
    stA(kt + 2, 0, p);
    __builtin_amdgcn_s_barrier();
    __builtin_amdgcn_s_setprio(1);
#pragma unroll
    for (int m = 0; m < 4; ++m)
#pragma unroll
      for (int n = 0; n < 4; ++n)
        acc[m][n] = __builtin_amdgcn_mfma_f32_16x16x32_bf16(a1[m], b1[n], acc[m][n], 0, 0, 0);
    __builtin_amdgcn_s_setprio(0);
    __builtin_amdgcn_sched_barrier(0);
    __builtin_amdgcn_s_barrier();
    // ---------- phase 4: stage A1(kt+2)->p | MFMA m4-7 kk1 | vmcnt(4)
    stA(kt + 2, 1, p);
    __builtin_amdgcn_s_barrier();
    __builtin_amdgcn_s_setprio(1);
#pragma unroll
    for (int m = 4; m < 8; ++m)
#pragma unroll
      for (int n = 0; n < 4; ++n)
        acc[m][n] = __builtin_amdgcn_mfma_f32_16x16x32_bf16(a1[m], b1[n], acc[m][n], 0, 0, 0);
    __builtin_amdgcn_s_setprio(0);
    // force kt+1's 4 units complete; leave kt+2's A0,A1 (4 loads) in flight
    asm volatile("s_waitcnt vmcnt(4)" ::: "memory");
    __builtin_amdgcn_sched_barrier(0);
    __builtin_amdgcn_s_barrier();
  };

  for (int kt = 0; kt < 16; kt += 2) {
    ktile(0, kt);
    ktile(1, kt + 1);
  }

  // epilogue: sigmoid(acc + bias) -> bf16 D  (acc-only; no LDS reads)
  const int rq = lane >> 4;
#pragma unroll
  for (int n = 0; n < 4; ++n) {
    const int col = n0 + wn + n * 16 + cl;
    const float bv = bias[col];
#pragma unroll
    for (int M = 0; M < 8; ++M) {
      const int rowb = m0 + wm + M * 16 + rq * 4;
#pragma unroll
      for (int i = 0; i < 4; ++i) {
        float v = acc[M][n][i] + bv;
        float s = 1.0f / (1.0f + __expf(-v));
        D[(size_t)(rowb + i) * NNODE + col] = f2bf(s);
      }
    }
  }
}

// ============ GEMM2: out = mu @ PT^T (128x128 tile) ============
__global__ __launch_bounds__(256)
void k_gemm2(const unsigned short* __restrict__ A, const unsigned short* __restrict__ Bt,
             float* __restrict__ outF) {
  __shared__ __align__(16) unsigned short As[128 * 64];
  __shared__ __align__(16) unsigned short Bs[128 * 64];
  const int t = threadIdx.x;
  const int lane = t & 63;
  const int wave = t >> 6;
  const int m0 = blockIdx.x * 128;
  const int wm = (wave >> 1) * 64;
  const int wn = (wave & 1) * 64;
  const int kg = t & 7;

  f32x4 acc[4][4];
#pragma unroll
  for (int i = 0; i < 4; ++i)
#pragma unroll
    for (int j = 0; j < 4; ++j) acc[i][j] = (f32x4)0.f;

  for (int kt = 0; kt < KD / 64; ++kt) {
    const int k0 = kt * 64;
#pragma unroll
    for (int j = 0; j < 4; ++j) {
      int row = j * 32 + (t >> 3);
      gload_lds16(A + (size_t)(m0 + row) * KD + k0 + kg * 8,
                  As + (size_t)(j * 256 + (t & ~63)) * 8);
      gload_lds16(Bt + (size_t)row * KD + k0 + kg * 8,
                  Bs + (size_t)(j * 256 + (t & ~63)) * 8);
    }
    __syncthreads();
#pragma unroll
    for (int kk = 0; kk < 2; ++kk) {
      bf16x8 af[4], bfr[4];
      const int kl = kk * 32 + (lane >> 4) * 8;
#pragma unroll
      for (int m = 0; m < 4; ++m)
        af[m] = ld_frag(As + (wm + m * 16 + (lane & 15)) * 64 + kl);
#pragma unroll
      for (int n = 0; n < 4; ++n)
        bfr[n] = ld_frag(Bs + (wn + n * 16 + (lane & 15)) * 64 + kl);
#pragma unroll
      for (int m = 0; m < 4; ++m)
#pragma unroll
        for (int n = 0; n < 4; ++n)
          acc[m][n] = __builtin_amdgcn_mfma_f32_16x16x32_bf16(af[m], bfr[n], acc[m][n], 0, 0, 0);
    }
    __syncthreads();
  }

  const int cl = lane & 15;
  const int rq = lane >> 4;
#pragma unroll
  for (int n = 0; n < 4; ++n) {
    int col = wn + n * 16 + cl;
    if (col < NCLS) {
#pragma unroll
      for (int m = 0; m < 4; ++m) {
        int rbase = m0 + wm + m * 16 + rq * 4;
#pragma unroll
        for (int i = 0; i < 4; ++i)
          outF[(size_t)(rbase + i) * NCLS + col] = acc[m][n][i];
      }
    }
  }
}

// ---- tree routing: in-place D row (d values) -> mu values ----
__global__ void k_route(unsigned short* __restrict__ D) {
  __shared__ float dsh[NNODE];
  int b = blockIdx.x, t = threadIdx.x;
  unsigned short* row = D + (size_t)b * NNODE;
  ushort4 v = *(const ushort4*)(row + t * 4);
  dsh[t * 4 + 0] = bf2f(v.x);
  dsh[t * 4 + 1] = bf2f(v.y);
  dsh[t * 4 + 2] = bf2f(v.z);
  dsh[t * 4 + 3] = bf2f(v.w);
  __syncthreads();
  ushort4 o;
  unsigned short* op = (unsigned short*)&o;
#pragma unroll
  for (int j = 0; j < 4; ++j) {
    int l = t * 4 + j;
    float p = 1.0f;
#pragma unroll
    for (int k = 0; k < 10; ++k) {
      int node = (1 << k) + (l >> (10 - k));
      float dv = dsh[node];
      p *= ((l >> (9 - k)) & 1) ? (1.0f - dv) : dv;
    }
    op[j] = f2bf(p);
  }
  *(ushort4*)(row + t * 4) = o;
}

extern "C" void kernel_launch(void* const* d_in, const int* in_sizes, int n_in,
                              void* d_out, int out_size, void* d_ws, size_t ws_size,
                              hipStream_t stream) {
  const float* features = (const float*)d_in[0]; // [16384][2048]
  const float* mask     = (const float*)d_in[1]; // [1024][2048]
  const float* W        = (const float*)d_in[2]; // [1024][1024]
  const float* bias     = (const float*)d_in[3]; // [1024]
  const float* pi       = (const float*)d_in[4]; // [1024][100]
  float* out = (float*)d_out;                    // [16384][100]

  char* ws = (char*)d_ws;
  int* idx           = (int*)ws;                                    // 4 KiB
  unsigned short* WT = (unsigned short*)(ws + 4096);                // 2 MiB [1024][1024]
  unsigned short* PT = (unsigned short*)(ws + 4096 + (1u << 21));   // 256 KiB [128][1024]
  unsigned short* X  = (unsigned short*)(ws + 4096 + (1u << 21) + (1u << 18)); // 32 MiB
  unsigned short* D  = (unsigned short*)(ws + 4096 + (1u << 21) + (1u << 18) + (1u << 25)); // 32 MiB

  k_idx<<<dim3(KD), dim3(256), 0, stream>>>(mask, idx);
  k_wt<<<dim3(32, 32), dim3(32, 8), 0, stream>>>(W, WT);
  k_probs<<<dim3(NNODE), dim3(64), 0, stream>>>(pi, PT);
  k_gather<<<dim3(BATCH), dim3(256), 0, stream>>>(features, idx, X);
  k_gemm1<<<dim3(BATCH / 256, NNODE / 256), dim3(512), 0, stream>>>(X, WT, bias, D);
  k_route<<<dim3(BATCH), dim3(256), 0, stream>>>(D);
  k_gemm2<<<dim3(BATCH / 128, 1), dim3(256), 0, stream>>>(D, PT, out);
}